// Round 1
// baseline (100.024 us; speedup 1.0000x reference)
//
#include <hip/hip_runtime.h>

// GraphAttentionLayer (GAT) fused pipeline for MI355X / gfx950.
//   h = x@W; s1 = x@(W@a1); s2 = x@(W@a2);
//   e_ij = leaky(s1_i + s2_j); attn = softmax_j(e); out = attn @ h
// Kernels:
//   k_wa : Wa1 = W@a1, Wa2 = W@a2 (fp32) -> exact score path
//   k_wt : Wt = W^T as bf16 (so GEMM B-tiles stage via global_load_lds)
//   k_h  : h = x@W via 16x16x32 bf16 MFMA; h stored octet-blocked
//          h_oct[row/8][col][row%8] (bf16) so PV B-frags are 16B-linear.
//          Also computes s1,s2 fp32 (fused; x staged once).
//   k_mz : per-row softmax stats m_i, 1/Z_i (rank-1 logits => precompute).
//   k_pv : out = P @ h. P generated on the fly (fp32 exp -> bf16 -> LDS),
//          V staged from h_oct via global_load_lds, fp32 accumulate.
// k-slot note: A and B fragments both use slot = 8*(lane>>4)+b for k; any
// internal k permutation cancels (k is a reduction index). D layout (m89):
// col = lane&15, row = 4*(lane>>4)+reg.

typedef unsigned short u16;
typedef unsigned int   u32;
typedef float f32x4 __attribute__((ext_vector_type(4)));
typedef u32   u32x4 __attribute__((ext_vector_type(4)));
typedef u32   u32x2 __attribute__((ext_vector_type(2)));
typedef __bf16 bf16x8 __attribute__((ext_vector_type(8)));

#define NB    64
#define NENT  1024
#define FD    256
#define NROWS (NB * NENT)
#define ALPHA 0.2f

__device__ __forceinline__ u16 f2b(float f) {          // fp32 -> bf16 RNE
  u32 u = __builtin_bit_cast(u32, f);
  u32 r = u + 0x7FFFu + ((u >> 16) & 1u);
  return (u16)(r >> 16);
}

typedef __attribute__((address_space(1))) const void* gas_ptr;
typedef __attribute__((address_space(3))) void*       las_ptr;
__device__ __forceinline__ void gload16(const void* g, void* l) {
  __builtin_amdgcn_global_load_lds((gas_ptr)g, (las_ptr)l, 16, 0, 0);
}

// ---------------- k_wa: Wa1 = W@a1, Wa2 = W@a2 ----------------
__global__ __launch_bounds__(256) void k_wa(const float* __restrict__ W,
                                            const float* __restrict__ a,
                                            float* __restrict__ Wa1,
                                            float* __restrict__ Wa2) {
  const int k = blockIdx.x, f = threadIdx.x;
  const float w = W[(size_t)k * FD + f];
  float p1 = w * a[f];
  float p2 = w * a[FD + f];
#pragma unroll
  for (int off = 1; off < 64; off <<= 1) {
    p1 += __shfl_xor(p1, off, 64);
    p2 += __shfl_xor(p2, off, 64);
  }
  __shared__ float r1[4], r2[4];
  const int wv = f >> 6, lane = f & 63;
  if (lane == 0) { r1[wv] = p1; r2[wv] = p2; }
  __syncthreads();
  if (f == 0) {
    Wa1[k] = r1[0] + r1[1] + r1[2] + r1[3];
    Wa2[k] = r2[0] + r2[1] + r2[2] + r2[3];
  }
}

// ---------------- k_wt: Wt[f][k] = bf16(W[k][f]) ----------------
__global__ __launch_bounds__(256) void k_wt(const float* __restrict__ W,
                                            u16* __restrict__ Wt) {
  __shared__ float tile[64][65];
  const int t = threadIdx.x;
  const int ki = blockIdx.x >> 2, fi = blockIdx.x & 3;
  const int k0 = ki * 64, f0 = fi * 64;
  const int r = t >> 4, c4 = (t & 15) * 4;
#pragma unroll
  for (int it = 0; it < 4; ++it) {
    const int row = r + it * 16;
    float4 v = *(const float4*)&W[(size_t)(k0 + row) * FD + f0 + c4];
    tile[row][c4 + 0] = v.x; tile[row][c4 + 1] = v.y;
    tile[row][c4 + 2] = v.z; tile[row][c4 + 3] = v.w;
  }
  __syncthreads();
#pragma unroll
  for (int it = 0; it < 4; ++it) {
    const int fr = r + it * 16;
    u32x2 pk;
    pk.x = f2b(tile[c4 + 0][fr]) | ((u32)f2b(tile[c4 + 1][fr]) << 16);
    pk.y = f2b(tile[c4 + 2][fr]) | ((u32)f2b(tile[c4 + 3][fr]) << 16);
    *(u32x2*)&Wt[(size_t)(f0 + fr) * FD + k0 + c4] = pk;
  }
}

// ---------------- k_h: h_oct = bf16(x@W), s1, s2 ----------------
__global__ __launch_bounds__(512, 2) void k_h(
    const float* __restrict__ x, const u16* __restrict__ Wt,
    const float* __restrict__ Wa1g, const float* __restrict__ Wa2g,
    u16* __restrict__ h_oct, float* __restrict__ s1, float* __restrict__ s2) {
  __shared__ __align__(16) u16 A_lds[4][128][8];   // [kslot-grp][row][8]
  __shared__ __align__(16) u16 B_lds[4][256][8];   // [kslot-grp][col][8]
  __shared__ float wa1[FD], wa2[FD];
  const int t = threadIdx.x;
  const int lane = t & 63, wv = t >> 6;
  const int wr = wv >> 2, wc = wv & 3;        // wave tile: 2 x 4 of 64x64
  const int g16 = lane >> 4, c15 = lane & 15;
  const int rT = blockIdx.x * 128;
  if (t < FD) { wa1[t] = Wa1g[t]; wa2[t] = Wa2g[t]; }
  const int srow = t >> 2, spart = t & 3;     // staging: 4 thr/row, 8 k each
  const float* xsrc = x + (size_t)(rT + srow) * FD + spart * 8;
  float p1 = 0.f, p2 = 0.f;
  f32x4 acc[4][4];
  const f32x4 vz = {0.f, 0.f, 0.f, 0.f};
#pragma unroll
  for (int i = 0; i < 4; ++i)
#pragma unroll
    for (int j = 0; j < 4; ++j) acc[i][j] = vz;

#pragma unroll 1
  for (int ks = 0; ks < 8; ++ks) {
    const int k0 = ks * 32;
    __syncthreads();
    // ---- stage A (x -> bf16) + fused s1/s2 partial dot ----
    float4 f0 = *(const float4*)(xsrc + k0);
    float4 f1 = *(const float4*)(xsrc + k0 + 4);
    u32x4 aw;
    aw.x = f2b(f0.x) | ((u32)f2b(f0.y) << 16);
    aw.y = f2b(f0.z) | ((u32)f2b(f0.w) << 16);
    aw.z = f2b(f1.x) | ((u32)f2b(f1.y) << 16);
    aw.w = f2b(f1.z) | ((u32)f2b(f1.w) << 16);
    *(u32x4*)&A_lds[spart][srow][0] = aw;
    const int kb = k0 + spart * 8;
    p1 += f0.x*wa1[kb+0] + f0.y*wa1[kb+1] + f0.z*wa1[kb+2] + f0.w*wa1[kb+3]
        + f1.x*wa1[kb+4] + f1.y*wa1[kb+5] + f1.z*wa1[kb+6] + f1.w*wa1[kb+7];
    p2 += f0.x*wa2[kb+0] + f0.y*wa2[kb+1] + f0.z*wa2[kb+2] + f0.w*wa2[kb+3]
        + f1.x*wa2[kb+4] + f1.y*wa2[kb+5] + f1.z*wa2[kb+6] + f1.w*wa2[kb+7];
    // ---- stage B (Wt rows, already bf16) via global_load_lds ----
    {
      const int d0 = t;
      gload16(Wt + (size_t)(d0 & 255) * FD + k0 + (d0 >> 8) * 8,
              (char*)(&B_lds[0][0][0]) + d0 * 16);
      const int d1 = t + 512;
      gload16(Wt + (size_t)(d1 & 255) * FD + k0 + (d1 >> 8) * 8,
              (char*)(&B_lds[0][0][0]) + d1 * 16);
    }
    __syncthreads();
    // ---- fragments + MFMA ----
    bf16x8 af[4], bfv[4];
#pragma unroll
    for (int fi = 0; fi < 4; ++fi)
      af[fi] = __builtin_bit_cast(bf16x8,
               *(const u32x4*)&A_lds[g16][wr * 64 + fi * 16 + c15][0]);
#pragma unroll
    for (int fj = 0; fj < 4; ++fj)
      bfv[fj] = __builtin_bit_cast(bf16x8,
               *(const u32x4*)&B_lds[g16][wc * 64 + fj * 16 + c15][0]);
#pragma unroll
    for (int fi = 0; fi < 4; ++fi)
#pragma unroll
      for (int fj = 0; fj < 4; ++fj)
        acc[fi][fj] = __builtin_amdgcn_mfma_f32_16x16x32_bf16(
            af[fi], bfv[fj], acc[fi][fj], 0, 0, 0);
  }
  // ---- s1/s2: reduce 4 k-parts (adjacent lanes) ----
  p1 += __shfl_xor(p1, 1, 64); p1 += __shfl_xor(p1, 2, 64);
  p2 += __shfl_xor(p2, 1, 64); p2 += __shfl_xor(p2, 2, 64);
  if (spart == 0) { s1[rT + srow] = p1; s2[rT + srow] = p2; }
  // ---- epilogue: h_oct[oct][col][u], u = row&7; 8B/lane, fully dense ----
#pragma unroll
  for (int fi = 0; fi < 4; ++fi) {
    const int rowb = rT + wr * 64 + fi * 16 + 4 * g16;
    const int oct = rowb >> 3, u = rowb & 7;   // u in {0,4}
#pragma unroll
    for (int fj = 0; fj < 4; ++fj) {
      const int col = wc * 64 + fj * 16 + c15;
      u32x2 pk;
      pk.x = f2b(acc[fi][fj][0]) | ((u32)f2b(acc[fi][fj][1]) << 16);
      pk.y = f2b(acc[fi][fj][2]) | ((u32)f2b(acc[fi][fj][3]) << 16);
      *(u32x2*)((u16*)h_oct + ((size_t)oct * FD + col) * 8 + u) = pk;
    }
  }
}

// ---------------- k_mz: m_i, 1/Z_i ----------------
__global__ __launch_bounds__(256) void k_mz(const float* __restrict__ s1,
                                            const float* __restrict__ s2,
                                            float* __restrict__ mOut,
                                            float* __restrict__ rZOut) {
  __shared__ float s2l[NENT];
  __shared__ float red[4][64];
  const int t = threadIdx.x;
  const int b = blockIdx.x >> 4, q = blockIdx.x & 15;  // 64 rows per block
  *(float4*)&s2l[t * 4] = *(const float4*)&s2[(size_t)b * NENT + t * 4];
  const int rl = t & 63, ch = t >> 6;                  // 4 j-chunks of 256
  const int row = b * NENT + q * 64 + rl;
  const float s1v = s1[row];
  const int jb = ch * 256;
  __syncthreads();
  float m0 = -1e30f, m1 = -1e30f;
  for (int j = 0; j < 256; j += 2) {
    float e0 = s1v + s2l[jb + j];     e0 = fmaxf(e0, ALPHA * e0); m0 = fmaxf(m0, e0);
    float e1 = s1v + s2l[jb + j + 1]; e1 = fmaxf(e1, ALPHA * e1); m1 = fmaxf(m1, e1);
  }
  red[ch][rl] = fmaxf(m0, m1);
  __syncthreads();
  const float mv = fmaxf(fmaxf(red[0][rl], red[1][rl]),
                         fmaxf(red[2][rl], red[3][rl]));
  float z0 = 0.f, z1 = 0.f;
  for (int j = 0; j < 256; j += 2) {
    float e0 = s1v + s2l[jb + j];     e0 = fmaxf(e0, ALPHA * e0); z0 += __expf(e0 - mv);
    float e1 = s1v + s2l[jb + j + 1]; e1 = fmaxf(e1, ALPHA * e1); z1 += __expf(e1 - mv);
  }
  __syncthreads();
  red[ch][rl] = z0 + z1;
  __syncthreads();
  if (ch == 0) {
    mOut[row] = mv;
    rZOut[row] = 1.0f / (red[0][rl] + red[1][rl] + red[2][rl] + red[3][rl]);
  }
}

// ---------------- k_pv: out = softmax(e) @ h ----------------
__global__ __launch_bounds__(512, 2) void k_pv(
    const u16* __restrict__ h_oct, const float* __restrict__ s1,
    const float* __restrict__ s2, const float* __restrict__ mArr,
    const float* __restrict__ rZArr, float* __restrict__ out) {
  __shared__ __align__(16) u16 P_lds[4][128][8];   // [kslot-grp][i-row][8]
  __shared__ __align__(16) u16 V_lds[4][256][8];   // [kslot-grp][col][8]
  __shared__ float s2l[NENT];
  const int t = threadIdx.x;
  const int lane = t & 63, wv = t >> 6;
  const int wr = wv >> 2, wc = wv & 3;
  const int g16 = lane >> 4, c15 = lane & 15;
  const int b = blockIdx.x >> 3, itile = blockIdx.x & 7;
  const int i0 = itile * 128;
  const int irow = t & 127, gsl = t >> 7;   // p-gen: thread -> (i-row, k-grp)
  const int rowg = b * NENT + i0 + irow;
  const float s1v = s1[rowg];
  const float mv  = mArr[rowg];
  const float rv  = rZArr[rowg];
  *(float2*)&s2l[t * 2] = *(const float2*)&s2[(size_t)b * NENT + t * 2];
  f32x4 acc[4][4];
  const f32x4 vz = {0.f, 0.f, 0.f, 0.f};
#pragma unroll
  for (int i = 0; i < 4; ++i)
#pragma unroll
    for (int j = 0; j < 4; ++j) acc[i][j] = vz;
  const size_t obase = (size_t)b * (NENT / 8);   // octet base for batch b

#pragma unroll 1
  for (int ks = 0; ks < 32; ++ks) {
    const int j0 = ks * 32;
    __syncthreads();
    // ---- generate P tile (128 x 32) in bf16, identity k-slot order ----
    const int jb = j0 + gsl * 8;
    float pvv[8];
#pragma unroll
    for (int u = 0; u < 8; ++u) {
      float e = s1v + s2l[jb + u];
      e = fmaxf(e, ALPHA * e);              // leaky relu (alpha < 1)
      pvv[u] = __expf(e - mv) * rv;
    }
    u32x4 pw;
    pw.x = f2b(pvv[0]) | ((u32)f2b(pvv[1]) << 16);
    pw.y = f2b(pvv[2]) | ((u32)f2b(pvv[3]) << 16);
    pw.z = f2b(pvv[4]) | ((u32)f2b(pvv[5]) << 16);
    pw.w = f2b(pvv[6]) | ((u32)f2b(pvv[7]) << 16);
    *(u32x4*)&P_lds[gsl][irow][0] = pw;
    // ---- stage V from h_oct (16B linear global_load_lds) ----
    {
      const int d0 = t;
      gload16(h_oct + ((obase + (j0 >> 3) + (d0 >> 8)) * FD + (d0 & 255)) * 8,
              (char*)(&V_lds[0][0][0]) + d0 * 16);
      const int d1 = t + 512;
      gload16(h_oct + ((obase + (j0 >> 3) + (d1 >> 8)) * FD + (d1 & 255)) * 8,
              (char*)(&V_lds[0][0][0]) + d1 * 16);
    }
    __syncthreads();
    // ---- fragments + MFMA ----
    bf16x8 af[4], bfv[4];
#pragma unroll
    for (int fi = 0; fi < 4; ++fi)
      af[fi] = __builtin_bit_cast(bf16x8,
               *(const u32x4*)&P_lds[g16][wr * 64 + fi * 16 + c15][0]);
#pragma unroll
    for (int fj = 0; fj < 4; ++fj)
      bfv[fj] = __builtin_bit_cast(bf16x8,
               *(const u32x4*)&V_lds[g16][wc * 64 + fj * 16 + c15][0]);
#pragma unroll
    for (int fi = 0; fi < 4; ++fi)
#pragma unroll
      for (int fj = 0; fj < 4; ++fj)
        acc[fi][fj] = __builtin_amdgcn_mfma_f32_16x16x32_bf16(
            af[fi], bfv[fj], acc[fi][fj], 0, 0, 0);
  }
  // ---- epilogue: fp32 out, 64B-dense per 16-lane group ----
#pragma unroll
  for (int fi = 0; fi < 4; ++fi) {
    const int rloc = i0 + wr * 64 + fi * 16 + 4 * g16;
#pragma unroll
    for (int fj = 0; fj < 4; ++fj) {
      const int col = wc * 64 + fj * 16 + c15;
      float* o = out + ((size_t)b * NENT + rloc) * FD + col;
      o[0 * FD] = acc[fi][fj][0];
      o[1 * FD] = acc[fi][fj][1];
      o[2 * FD] = acc[fi][fj][2];
      o[3 * FD] = acc[fi][fj][3];
    }
  }
}

extern "C" void kernel_launch(void* const* d_in, const int* in_sizes, int n_in,
                              void* d_out, int out_size, void* d_ws, size_t ws_size,
                              hipStream_t stream) {
  const float* x = (const float*)d_in[0];
  const float* W = (const float*)d_in[1];
  const float* a = (const float*)d_in[2];
  float* out = (float*)d_out;

  char* ws = (char*)d_ws;
  u16*   h_oct = (u16*)ws;                         // 33,554,432 B
  float* s1  = (float*)(ws + (size_t)33554432);    // 256 KB
  float* s2  = s1 + NROWS;                         // 256 KB
  float* mB  = s2 + NROWS;                         // 256 KB
  float* rZ  = mB + NROWS;                         // 256 KB
  float* Wa1 = rZ + NROWS;                         // 1 KB
  float* Wa2 = Wa1 + FD;                           // 1 KB
  u16*   Wt  = (u16*)(Wa2 + FD);                   // 128 KB  (~34.8 MB total)

  k_wa<<<dim3(256), dim3(256), 0, stream>>>(W, a, Wa1, Wa2);
  k_wt<<<dim3(16), dim3(256), 0, stream>>>(W, Wt);
  k_h<<<dim3(NROWS / 128), dim3(512), 0, stream>>>(x, Wt, Wa1, Wa2, h_oct, s1, s2);
  k_mz<<<dim3(NB * 16), dim3(256), 0, stream>>>(s1, s2, mB, rZ);
  k_pv<<<dim3(NB * 8), dim3(512), 0, stream>>>(h_oct, s1, s2, mB, rZ, out);
}

// Round 2
// 81.883 us; speedup vs baseline: 1.2216x; 1.2216x over previous
//
#include <hip/hip_runtime.h>

// GAT fused pipeline, round 1: double-buffered single-barrier K-loops,
// k_mz folded away (monotone-leaky max trick + in-kernel Z accumulation),
// XCD-chunked block swizzle in k_pv for h L2 reuse.
//   h = x@W; s1 = x@(W@a1); s2 = x@(W@a2);  (score path exact fp32)
//   m_i = leaky(s1_i + max_j s2_j)          (leaky is monotone)
//   out_i = (sum_j exp(leaky(s1_i+s2_j)-m_i) h_j) / Z_i,  Z_i accumulated in k_pv.

typedef unsigned short u16;
typedef unsigned int   u32;
typedef float  f32x4  __attribute__((ext_vector_type(4)));
typedef __bf16 bf16x8 __attribute__((ext_vector_type(8)));
typedef __bf16 bf16x4 __attribute__((ext_vector_type(4)));

#define NB    64
#define NENT  1024
#define FD    256
#define NROWS (NB * NENT)
#define ALPHA 0.2f

typedef __attribute__((address_space(1))) const void* gas_ptr;
typedef __attribute__((address_space(3))) void*       las_ptr;
__device__ __forceinline__ void gload16(const void* g, void* l) {
  __builtin_amdgcn_global_load_lds((gas_ptr)g, (las_ptr)l, 16, 0, 0);
}

// ---------------- k_wa: Wa1 = W@a1, Wa2 = W@a2 (fp32 exact) ----------------
__global__ __launch_bounds__(256) void k_wa(const float* __restrict__ W,
                                            const float* __restrict__ a,
                                            float* __restrict__ Wa1,
                                            float* __restrict__ Wa2) {
  const int k = blockIdx.x, f = threadIdx.x;
  const float w = W[(size_t)k * FD + f];
  float p1 = w * a[f];
  float p2 = w * a[FD + f];
#pragma unroll
  for (int off = 1; off < 64; off <<= 1) {
    p1 += __shfl_xor(p1, off, 64);
    p2 += __shfl_xor(p2, off, 64);
  }
  __shared__ float r1[4], r2[4];
  const int wv = f >> 6, lane = f & 63;
  if (lane == 0) { r1[wv] = p1; r2[wv] = p2; }
  __syncthreads();
  if (f == 0) {
    Wa1[k] = r1[0] + r1[1] + r1[2] + r1[3];
    Wa2[k] = r2[0] + r2[1] + r2[2] + r2[3];
  }
}

// ---------------- k_wt: Wt[f][k] = bf16(W[k][f]) ----------------
__global__ __launch_bounds__(256) void k_wt(const float* __restrict__ W,
                                            u16* __restrict__ Wt) {
  __shared__ float tile[64][65];
  const int t = threadIdx.x;
  const int ki = blockIdx.x >> 2, fi = blockIdx.x & 3;
  const int k0 = ki * 64, f0 = fi * 64;
  const int r = t >> 4, c4 = (t & 15) * 4;
#pragma unroll
  for (int it = 0; it < 4; ++it) {
    const int row = r + it * 16;
    float4 v = *(const float4*)&W[(size_t)(k0 + row) * FD + f0 + c4];
    tile[row][c4 + 0] = v.x; tile[row][c4 + 1] = v.y;
    tile[row][c4 + 2] = v.z; tile[row][c4 + 3] = v.w;
  }
  __syncthreads();
#pragma unroll
  for (int it = 0; it < 4; ++it) {
    const int fr = r + it * 16;
    bf16x4 pk;
    pk[0] = (__bf16)tile[c4 + 0][fr]; pk[1] = (__bf16)tile[c4 + 1][fr];
    pk[2] = (__bf16)tile[c4 + 2][fr]; pk[3] = (__bf16)tile[c4 + 3][fr];
    *(bf16x4*)&Wt[(size_t)(f0 + fr) * FD + k0 + c4] = pk;
  }
}

// ---------------- k_h: h_oct = bf16(x@W), s1, s2 (dbuf pipeline) ----------------
__global__ __launch_bounds__(512, 2) void k_h(
    const float* __restrict__ x, const u16* __restrict__ Wt,
    const float* __restrict__ Wa1g, const float* __restrict__ Wa2g,
    u16* __restrict__ h_oct, float* __restrict__ s1, float* __restrict__ s2) {
  __shared__ __align__(16) u16 A_lds[2][4][128][8];   // [buf][kgrp][row][8]
  __shared__ __align__(16) u16 B_lds[2][4][256][8];   // [buf][kgrp][col][8]
  __shared__ float wa1[FD], wa2[FD];
  const int t = threadIdx.x;
  const int lane = t & 63, wv = t >> 6;
  const int wr = wv >> 2, wc = wv & 3;          // wave tile 2x4 of 64x64
  const int g16 = lane >> 4, c15 = lane & 15;
  const int rT = blockIdx.x * 128;
  if (t < FD) { wa1[t] = Wa1g[t]; wa2[t] = Wa2g[t]; }
  const int srow = t >> 2, spart = t & 3;       // 4 threads/row, 8 k each
  const float* xsrc = x + (size_t)(rT + srow) * FD + spart * 8;
  float p1 = 0.f, p2 = 0.f;
  f32x4 acc[4][4];
  const f32x4 vz = {0.f, 0.f, 0.f, 0.f};
#pragma unroll
  for (int i = 0; i < 4; ++i)
#pragma unroll
    for (int j = 0; j < 4; ++j) acc[i][j] = vz;

  auto stage = [&](int nb, int kc, const float4& f0, const float4& f1) {
    const int k0n = kc * 32;
    const int d0 = t;
    gload16(Wt + (size_t)(d0 & 255) * FD + k0n + (d0 >> 8) * 8,
            (char*)(&B_lds[nb][0][0][0]) + d0 * 16);
    const int d1 = t + 512;
    gload16(Wt + (size_t)(d1 & 255) * FD + k0n + (d1 >> 8) * 8,
            (char*)(&B_lds[nb][0][0][0]) + d1 * 16);
    bf16x8 aw;
    aw[0] = (__bf16)f0.x; aw[1] = (__bf16)f0.y;
    aw[2] = (__bf16)f0.z; aw[3] = (__bf16)f0.w;
    aw[4] = (__bf16)f1.x; aw[5] = (__bf16)f1.y;
    aw[6] = (__bf16)f1.z; aw[7] = (__bf16)f1.w;
    *(bf16x8*)&A_lds[nb][spart][srow][0] = aw;
    const int kb = k0n + spart * 8;
    p1 += f0.x*wa1[kb+0] + f0.y*wa1[kb+1] + f0.z*wa1[kb+2] + f0.w*wa1[kb+3]
        + f1.x*wa1[kb+4] + f1.y*wa1[kb+5] + f1.z*wa1[kb+6] + f1.w*wa1[kb+7];
    p2 += f0.x*wa2[kb+0] + f0.y*wa2[kb+1] + f0.z*wa2[kb+2] + f0.w*wa2[kb+3]
        + f1.x*wa2[kb+4] + f1.y*wa2[kb+5] + f1.z*wa2[kb+6] + f1.w*wa2[kb+7];
  };
  auto mfma_step = [&](int cb) {
    bf16x8 af[4], bfv[4];
#pragma unroll
    for (int fi = 0; fi < 4; ++fi)
      af[fi] = *(const bf16x8*)&A_lds[cb][g16][wr * 64 + fi * 16 + c15][0];
#pragma unroll
    for (int fj = 0; fj < 4; ++fj)
      bfv[fj] = *(const bf16x8*)&B_lds[cb][g16][wc * 64 + fj * 16 + c15][0];
#pragma unroll
    for (int fi = 0; fi < 4; ++fi)
#pragma unroll
      for (int fj = 0; fj < 4; ++fj)
        acc[fi][fj] = __builtin_amdgcn_mfma_f32_16x16x32_bf16(
            af[fi], bfv[fj], acc[fi][fj], 0, 0, 0);
  };

  // prologue: chunk0 staged directly; chunk1/chunk2 prefetched to regs
  float4 xc0 = *(const float4*)(xsrc + 0);
  float4 xc1 = *(const float4*)(xsrc + 4);
  float4 xb0 = *(const float4*)(xsrc + 32);
  float4 xb1 = *(const float4*)(xsrc + 36);
  float4 xa0 = *(const float4*)(xsrc + 64);
  float4 xa1 = *(const float4*)(xsrc + 68);
  __syncthreads();                 // wa1/wa2 visible
  stage(0, 0, xc0, xc1);
  __syncthreads();                 // A[0] written, B[0] arrived
#pragma unroll 1
  for (int ks2 = 0; ks2 < 4; ++ks2) {
    // half A: stage chunk 2k+1 into buf1, MFMA chunk 2k from buf0
    stage(1, 2 * ks2 + 1, xb0, xb1);
    if (2 * ks2 + 3 < 8) {
      xb0 = *(const float4*)(xsrc + (2 * ks2 + 3) * 32);
      xb1 = *(const float4*)(xsrc + (2 * ks2 + 3) * 32 + 4);
    }
    mfma_step(0);
    __syncthreads();
    // half B: stage chunk 2k+2 into buf0, MFMA chunk 2k+1 from buf1
    if (2 * ks2 + 2 < 8) {
      stage(0, 2 * ks2 + 2, xa0, xa1);
      if (2 * ks2 + 4 < 8) {
        xa0 = *(const float4*)(xsrc + (2 * ks2 + 4) * 32);
        xa1 = *(const float4*)(xsrc + (2 * ks2 + 4) * 32 + 4);
      }
    }
    mfma_step(1);
    __syncthreads();
  }
  // s1/s2: reduce the 4 k-part lanes (spart = t&3 -> xor 1,2)
  p1 += __shfl_xor(p1, 1, 64); p1 += __shfl_xor(p1, 2, 64);
  p2 += __shfl_xor(p2, 1, 64); p2 += __shfl_xor(p2, 2, 64);
  if (spart == 0) { s1[rT + srow] = p1; s2[rT + srow] = p2; }
  // epilogue: h_oct[oct][col][row&7], 8B dense stores
#pragma unroll
  for (int fi = 0; fi < 4; ++fi) {
    const int rowb = rT + wr * 64 + fi * 16 + 4 * g16;
    const int oct = rowb >> 3, u = rowb & 7;    // u in {0,4}
#pragma unroll
    for (int fj = 0; fj < 4; ++fj) {
      const int col = wc * 64 + fj * 16 + c15;
      bf16x4 pk;
      pk[0] = (__bf16)acc[fi][fj][0]; pk[1] = (__bf16)acc[fi][fj][1];
      pk[2] = (__bf16)acc[fi][fj][2]; pk[3] = (__bf16)acc[fi][fj][3];
      *(bf16x4*)((u16*)h_oct + ((size_t)oct * FD + col) * 8 + u) = pk;
    }
  }
}

// ---------------- k_pv: out = softmax(e) @ h (dbuf, fused Z, XCD swizzle) ----
__global__ __launch_bounds__(512, 2) void k_pv(
    const u16* __restrict__ h_oct, const float* __restrict__ s1,
    const float* __restrict__ s2, float* __restrict__ out) {
  __shared__ __align__(16) u16 P_lds[2][4][128][8];
  __shared__ __align__(16) u16 V_lds[2][4][256][8];
  __shared__ float s2l[NENT];
  const int t = threadIdx.x;
  const int lane = t & 63, wv = t >> 6;
  const int wr = wv >> 2, wc = wv & 3;
  const int g16 = lane >> 4, c15 = lane & 15;
  // XCD-chunked swizzle: physical p -> XCD p%8; give each XCD 8 whole batches.
  const int p = blockIdx.x;
  const int lb = (p & 7) * 64 + (p >> 3);
  const int b = lb >> 3, itile = lb & 7;
  const int i0 = itile * 128;
  const int irow = t & 127, gsl = t >> 7;
  const int rowg = b * NENT + i0 + irow;
  const float s1v = s1[rowg];
  const size_t obase = (size_t)b * (NENT / 8);
  f32x4 acc[4][4];
  const f32x4 vz = {0.f, 0.f, 0.f, 0.f};
#pragma unroll
  for (int i = 0; i < 4; ++i)
#pragma unroll
    for (int j = 0; j < 4; ++j) acc[i][j] = vz;
  float zsum = 0.f;

  auto vload = [&](int nb, int ksn) {
    const int j0n = ksn * 32;
    const int d0 = t;
    gload16(h_oct + ((obase + (j0n >> 3) + (d0 >> 8)) * FD + (d0 & 255)) * 8,
            (char*)(&V_lds[nb][0][0][0]) + d0 * 16);
    const int d1 = t + 512;
    gload16(h_oct + ((obase + (j0n >> 3) + (d1 >> 8)) * FD + (d1 & 255)) * 8,
            (char*)(&V_lds[nb][0][0][0]) + d1 * 16);
  };

  // V[0] can be issued before anything else (no dependence on s2l)
  vload(0, 0);
  *(float2*)&s2l[t * 2] = *(const float2*)&s2[(size_t)b * NENT + t * 2];
  __syncthreads();                 // s2l visible
  // m_i = leaky(s1_i + max_j s2_j): leaky is monotone, so one max suffices.
  float sm = s2l[lane];
#pragma unroll
  for (int j = 1; j < 16; ++j) sm = fmaxf(sm, s2l[lane + j * 64]);
#pragma unroll
  for (int off = 1; off < 64; off <<= 1) sm = fmaxf(sm, __shfl_xor(sm, off, 64));
  const float q = s1v + sm;
  const float mv = fmaxf(q, ALPHA * q);

  auto genp = [&](int nb, int ksn) {
    const int jb = ksn * 32 + gsl * 8;
    bf16x8 pw;
    float zp = 0.f;
#pragma unroll
    for (int u = 0; u < 8; ++u) {
      float z = s1v + s2l[jb + u];
      float l = fmaxf(z, ALPHA * z);
      float pe = __expf(l - mv);
      zp += pe;
      pw[u] = (__bf16)pe;
    }
    zsum += zp;
    *(bf16x8*)&P_lds[nb][gsl][irow][0] = pw;
  };
  auto mfma_step = [&](int cb) {
    bf16x8 af[4], bfv[4];
#pragma unroll
    for (int fi = 0; fi < 4; ++fi)
      af[fi] = *(const bf16x8*)&P_lds[cb][g16][wr * 64 + fi * 16 + c15][0];
#pragma unroll
    for (int fj = 0; fj < 4; ++fj)
      bfv[fj] = *(const bf16x8*)&V_lds[cb][g16][wc * 64 + fj * 16 + c15][0];
#pragma unroll
    for (int fi = 0; fi < 4; ++fi)
#pragma unroll
      for (int fj = 0; fj < 4; ++fj)
        acc[fi][fj] = __builtin_amdgcn_mfma_f32_16x16x32_bf16(
            af[fi], bfv[fj], acc[fi][fj], 0, 0, 0);
  };

  genp(0, 0);
  __syncthreads();                 // P[0] written, V[0] arrived
#pragma unroll 1
  for (int ks2 = 0; ks2 < 16; ++ks2) {
    // half A: prefetch step 2k+1 into buf1, compute step 2k from buf0
    vload(1, 2 * ks2 + 1);
    genp(1, 2 * ks2 + 1);
    mfma_step(0);
    __syncthreads();
    // half B: prefetch step 2k+2 into buf0, compute step 2k+1 from buf1
    if (2 * ks2 + 2 < 32) {
      vload(0, 2 * ks2 + 2);
      genp(0, 2 * ks2 + 2);
    }
    mfma_step(1);
    __syncthreads();
  }
  // Z reduction (alias zred onto P_lds[0]; all MFMA reads are barrier-complete)
  float* zred = (float*)&P_lds[0][0][0][0];
  zred[gsl * 128 + irow] = zsum;
  __syncthreads();
  // epilogue: out = acc / Z
#pragma unroll
  for (int fi = 0; fi < 4; ++fi) {
    const int rowb = wr * 64 + fi * 16 + 4 * g16;
    float rz[4];
#pragma unroll
    for (int r = 0; r < 4; ++r)
      rz[r] = 1.0f / (zred[rowb + r] + zred[128 + rowb + r] +
                      zred[256 + rowb + r] + zred[384 + rowb + r]);
#pragma unroll
    for (int fj = 0; fj < 4; ++fj) {
      const int col = wc * 64 + fj * 16 + c15;
      float* o = out + ((size_t)b * NENT + i0 + rowb) * FD + col;
      o[0 * FD] = acc[fi][fj][0] * rz[0];
      o[1 * FD] = acc[fi][fj][1] * rz[1];
      o[2 * FD] = acc[fi][fj][2] * rz[2];
      o[3 * FD] = acc[fi][fj][3] * rz[3];
    }
  }
}

extern "C" void kernel_launch(void* const* d_in, const int* in_sizes, int n_in,
                              void* d_out, int out_size, void* d_ws, size_t ws_size,
                              hipStream_t stream) {
  const float* x = (const float*)d_in[0];
  const float* W = (const float*)d_in[1];
  const float* a = (const float*)d_in[2];
  float* out = (float*)d_out;

  char* ws = (char*)d_ws;
  u16*   h_oct = (u16*)ws;                       // 32 MB
  float* s1  = (float*)(ws + (size_t)33554432);  // 256 KB
  float* s2  = s1 + NROWS;                       // 256 KB
  float* Wa1 = s2 + NROWS;                       // 1 KB
  float* Wa2 = Wa1 + FD;                         // 1 KB
  u16*   Wt  = (u16*)(Wa2 + FD);                 // 128 KB

  k_wa<<<dim3(256), dim3(256), 0, stream>>>(W, a, Wa1, Wa2);
  k_wt<<<dim3(16), dim3(256), 0, stream>>>(W, Wt);
  k_h<<<dim3(NROWS / 128), dim3(512), 0, stream>>>(x, Wt, Wa1, Wa2, h_oct, s1, s2);
  k_pv<<<dim3(NB * 8), dim3(512), 0, stream>>>(h_oct, s1, s2, out);
}

// Round 3
// 78.618 us; speedup vs baseline: 1.2723x; 1.0415x over previous
//
#include <hip/hip_runtime.h>

// GAT fused pipeline, round 2: 256x256 block tiles (FLOP/LDS-byte +33%),
// exp2-domain fused P-gen, both GEMM kernels XCD-swizzled identically.
//   h = x@W; s1 = x@(W@a1); s2 = x@(W@a2);  (score path exact fp32)
//   m_i = leaky(s1_i + max_j s2_j)          (leaky is monotone)
//   out_i = (sum_j exp(leaky(s1_i+s2_j)-m_i) h_j) / Z_i,  Z accumulated in k_pv.

typedef unsigned short u16;
typedef unsigned int   u32;
typedef float  f32x4  __attribute__((ext_vector_type(4)));
typedef __bf16 bf16x8 __attribute__((ext_vector_type(8)));
typedef __bf16 bf16x4 __attribute__((ext_vector_type(4)));

#define NB    64
#define NENT  1024
#define FD    256
#define NROWS (NB * NENT)
#define ALPHA 0.2f
#define LOG2E 1.4426950408889634f

typedef __attribute__((address_space(1))) const void* gas_ptr;
typedef __attribute__((address_space(3))) void*       las_ptr;
__device__ __forceinline__ void gload16(const void* g, void* l) {
  __builtin_amdgcn_global_load_lds((gas_ptr)g, (las_ptr)l, 16, 0, 0);
}
__device__ __forceinline__ float fexp2(float x) {   // 2^x, 1-instr
  float r;
  asm("v_exp_f32 %0, %1" : "=v"(r) : "v"(x));
  return r;
}

// ---------------- k_wa: Wa1 = W@a1, Wa2 = W@a2 (fp32 exact) ----------------
__global__ __launch_bounds__(256) void k_wa(const float* __restrict__ W,
                                            const float* __restrict__ a,
                                            float* __restrict__ Wa1,
                                            float* __restrict__ Wa2) {
  const int k = blockIdx.x, f = threadIdx.x;
  const float w = W[(size_t)k * FD + f];
  float p1 = w * a[f];
  float p2 = w * a[FD + f];
#pragma unroll
  for (int off = 1; off < 64; off <<= 1) {
    p1 += __shfl_xor(p1, off, 64);
    p2 += __shfl_xor(p2, off, 64);
  }
  __shared__ float r1[4], r2[4];
  const int wv = f >> 6, lane = f & 63;
  if (lane == 0) { r1[wv] = p1; r2[wv] = p2; }
  __syncthreads();
  if (f == 0) {
    Wa1[k] = r1[0] + r1[1] + r1[2] + r1[3];
    Wa2[k] = r2[0] + r2[1] + r2[2] + r2[3];
  }
}

// ---------------- k_wt: Wt[f][k] = bf16(W[k][f]) ----------------
__global__ __launch_bounds__(256) void k_wt(const float* __restrict__ W,
                                            u16* __restrict__ Wt) {
  __shared__ float tile[64][65];
  const int t = threadIdx.x;
  const int ki = blockIdx.x >> 2, fi = blockIdx.x & 3;
  const int k0 = ki * 64, f0 = fi * 64;
  const int r = t >> 4, c4 = (t & 15) * 4;
#pragma unroll
  for (int it = 0; it < 4; ++it) {
    const int row = r + it * 16;
    float4 v = *(const float4*)&W[(size_t)(k0 + row) * FD + f0 + c4];
    tile[row][c4 + 0] = v.x; tile[row][c4 + 1] = v.y;
    tile[row][c4 + 2] = v.z; tile[row][c4 + 3] = v.w;
  }
  __syncthreads();
#pragma unroll
  for (int it = 0; it < 4; ++it) {
    const int fr = r + it * 16;
    bf16x4 pk;
    pk[0] = (__bf16)tile[c4 + 0][fr]; pk[1] = (__bf16)tile[c4 + 1][fr];
    pk[2] = (__bf16)tile[c4 + 2][fr]; pk[3] = (__bf16)tile[c4 + 3][fr];
    *(bf16x4*)&Wt[(size_t)(f0 + fr) * FD + k0 + c4] = pk;
  }
}

// ---------------- k_h: h_oct = bf16(x@W), s1, s2 (256x256 tile) ----------------
__global__ __launch_bounds__(512, 2) void k_h(
    const float* __restrict__ x, const u16* __restrict__ Wt,
    const float* __restrict__ Wa1g, const float* __restrict__ Wa2g,
    u16* __restrict__ h_oct, float* __restrict__ s1, float* __restrict__ s2) {
  __shared__ __align__(16) u16 A_lds[2][4][256][8];   // [buf][kgrp][row][8]
  __shared__ __align__(16) u16 B_lds[2][4][256][8];   // [buf][kgrp][col][8]
  __shared__ float wa1[FD], wa2[FD];
  const int t = threadIdx.x;
  const int lane = t & 63, wv = t >> 6;
  const int wr = wv >> 2, wc = wv & 3;          // wave tile 128x64 (2x4 grid)
  const int g16 = lane >> 4, c15 = lane & 15;
  const int p = blockIdx.x;
  const int lb = (p & 7) * 32 + (p >> 3);       // XCD-chunked (same map as k_pv)
  const int rT = lb * 256;
  if (t < FD) { wa1[t] = Wa1g[t]; wa2[t] = Wa2g[t]; }
  const int row = t >> 1, half = t & 1;         // staging: 2 thr/row, 16 k each
  const float* xsrc = x + (size_t)(rT + row) * FD + half * 16;
  float p1 = 0.f, p2 = 0.f;
  f32x4 acc[8][4];
  const f32x4 vz = {0.f, 0.f, 0.f, 0.f};
#pragma unroll
  for (int i = 0; i < 8; ++i)
#pragma unroll
    for (int j = 0; j < 4; ++j) acc[i][j] = vz;

  auto stage = [&](int nb, int kc, const float4& f0, const float4& f1,
                   const float4& f2, const float4& f3) {
    const int k0n = kc * 32;
    const int d0 = t;
    gload16(Wt + (size_t)(d0 & 255) * FD + k0n + (d0 >> 8) * 8,
            (char*)(&B_lds[nb][0][0][0]) + d0 * 16);
    const int d1 = t + 512;
    gload16(Wt + (size_t)(d1 & 255) * FD + k0n + (d1 >> 8) * 8,
            (char*)(&B_lds[nb][0][0][0]) + d1 * 16);
    bf16x8 w0, w1;
    w0[0] = (__bf16)f0.x; w0[1] = (__bf16)f0.y;
    w0[2] = (__bf16)f0.z; w0[3] = (__bf16)f0.w;
    w0[4] = (__bf16)f1.x; w0[5] = (__bf16)f1.y;
    w0[6] = (__bf16)f1.z; w0[7] = (__bf16)f1.w;
    w1[0] = (__bf16)f2.x; w1[1] = (__bf16)f2.y;
    w1[2] = (__bf16)f2.z; w1[3] = (__bf16)f2.w;
    w1[4] = (__bf16)f3.x; w1[5] = (__bf16)f3.y;
    w1[6] = (__bf16)f3.z; w1[7] = (__bf16)f3.w;
    *(bf16x8*)&A_lds[nb][half * 2][row][0] = w0;
    *(bf16x8*)&A_lds[nb][half * 2 + 1][row][0] = w1;
    const int kb = k0n + half * 16;
    p1 += f0.x*wa1[kb+ 0] + f0.y*wa1[kb+ 1] + f0.z*wa1[kb+ 2] + f0.w*wa1[kb+ 3]
        + f1.x*wa1[kb+ 4] + f1.y*wa1[kb+ 5] + f1.z*wa1[kb+ 6] + f1.w*wa1[kb+ 7]
        + f2.x*wa1[kb+ 8] + f2.y*wa1[kb+ 9] + f2.z*wa1[kb+10] + f2.w*wa1[kb+11]
        + f3.x*wa1[kb+12] + f3.y*wa1[kb+13] + f3.z*wa1[kb+14] + f3.w*wa1[kb+15];
    p2 += f0.x*wa2[kb+ 0] + f0.y*wa2[kb+ 1] + f0.z*wa2[kb+ 2] + f0.w*wa2[kb+ 3]
        + f1.x*wa2[kb+ 4] + f1.y*wa2[kb+ 5] + f1.z*wa2[kb+ 6] + f1.w*wa2[kb+ 7]
        + f2.x*wa2[kb+ 8] + f2.y*wa2[kb+ 9] + f2.z*wa2[kb+10] + f2.w*wa2[kb+11]
        + f3.x*wa2[kb+12] + f3.y*wa2[kb+13] + f3.z*wa2[kb+14] + f3.w*wa2[kb+15];
  };
  auto mfma_step = [&](int cb) {
    bf16x8 bfv[4];
#pragma unroll
    for (int fj = 0; fj < 4; ++fj)
      bfv[fj] = *(const bf16x8*)&B_lds[cb][g16][wc * 64 + fj * 16 + c15][0];
#pragma unroll
    for (int fi = 0; fi < 8; ++fi) {
      bf16x8 af = *(const bf16x8*)&A_lds[cb][g16][wr * 128 + fi * 16 + c15][0];
#pragma unroll
      for (int fj = 0; fj < 4; ++fj)
        acc[fi][fj] = __builtin_amdgcn_mfma_f32_16x16x32_bf16(
            af, bfv[fj], acc[fi][fj], 0, 0, 0);
    }
  };

  // prologue: chunk0 direct; chunk1/chunk2 prefetched to regs
  float4 xc0 = *(const float4*)(xsrc +  0);
  float4 xc1 = *(const float4*)(xsrc +  4);
  float4 xc2 = *(const float4*)(xsrc +  8);
  float4 xc3 = *(const float4*)(xsrc + 12);
  float4 xb0 = *(const float4*)(xsrc + 32);
  float4 xb1 = *(const float4*)(xsrc + 36);
  float4 xb2 = *(const float4*)(xsrc + 40);
  float4 xb3 = *(const float4*)(xsrc + 44);
  float4 xa0 = *(const float4*)(xsrc + 64);
  float4 xa1 = *(const float4*)(xsrc + 68);
  float4 xa2 = *(const float4*)(xsrc + 72);
  float4 xa3 = *(const float4*)(xsrc + 76);
  __syncthreads();                 // wa1/wa2 visible
  stage(0, 0, xc0, xc1, xc2, xc3);
  __syncthreads();                 // A[0] written, B[0] arrived
#pragma unroll 1
  for (int ks2 = 0; ks2 < 4; ++ks2) {
    stage(1, 2 * ks2 + 1, xb0, xb1, xb2, xb3);
    if (2 * ks2 + 3 < 8) {
      const float* s = xsrc + (2 * ks2 + 3) * 32;
      xb0 = *(const float4*)(s);      xb1 = *(const float4*)(s + 4);
      xb2 = *(const float4*)(s + 8);  xb3 = *(const float4*)(s + 12);
    }
    mfma_step(0);
    __syncthreads();
    if (2 * ks2 + 2 < 8) {
      stage(0, 2 * ks2 + 2, xa0, xa1, xa2, xa3);
      if (2 * ks2 + 4 < 8) {
        const float* s = xsrc + (2 * ks2 + 4) * 32;
        xa0 = *(const float4*)(s);      xa1 = *(const float4*)(s + 4);
        xa2 = *(const float4*)(s + 8);  xa3 = *(const float4*)(s + 12);
      }
    }
    mfma_step(1);
    __syncthreads();
  }
  // s1/s2: reduce 2 k-halves (xor 1)
  p1 += __shfl_xor(p1, 1, 64);
  p2 += __shfl_xor(p2, 1, 64);
  if (half == 0) { s1[rT + row] = p1; s2[rT + row] = p2; }
  // epilogue: h_oct[oct][col][row&7], 8B dense stores
#pragma unroll
  for (int fi = 0; fi < 8; ++fi) {
    const int rowb = rT + wr * 128 + fi * 16 + 4 * g16;
    const int oct = rowb >> 3, u = rowb & 7;    // u in {0,4}
#pragma unroll
    for (int fj = 0; fj < 4; ++fj) {
      const int col = wc * 64 + fj * 16 + c15;
      bf16x4 pk;
      pk[0] = (__bf16)acc[fi][fj][0]; pk[1] = (__bf16)acc[fi][fj][1];
      pk[2] = (__bf16)acc[fi][fj][2]; pk[3] = (__bf16)acc[fi][fj][3];
      *(bf16x4*)((u16*)h_oct + ((size_t)oct * FD + col) * 8 + u) = pk;
    }
  }
}

// ---------------- k_pv: out = softmax(e) @ h (256x256 tile) ----------------
__global__ __launch_bounds__(512, 2) void k_pv(
    const u16* __restrict__ h_oct, const float* __restrict__ s1,
    const float* __restrict__ s2, float* __restrict__ out) {
  __shared__ __align__(16) u16 P_lds[2][4][256][8];
  __shared__ __align__(16) u16 V_lds[2][4][256][8];
  __shared__ float s2l[NENT];
  const int t = threadIdx.x;
  const int lane = t & 63, wv = t >> 6;
  const int wr = wv >> 2, wc = wv & 3;          // wave tile 128x64
  const int g16 = lane >> 4, c15 = lane & 15;
  const int p = blockIdx.x;
  const int lb = (p & 7) * 32 + (p >> 3);       // XCD-chunked: 8 batches/XCD
  const int b = lb >> 2, itile = lb & 3;
  const int i0 = itile * 256;
  const int irow = t & 255, gsl = t >> 8;       // p-gen: (i-row, j-half)
  const int rowg = b * NENT + i0 + irow;
  const float s1v = s1[rowg];
  const size_t obase = (size_t)b * (NENT / 8);
  f32x4 acc[8][4];
  const f32x4 vz = {0.f, 0.f, 0.f, 0.f};
#pragma unroll
  for (int i = 0; i < 8; ++i)
#pragma unroll
    for (int j = 0; j < 4; ++j) acc[i][j] = vz;
  float zsum = 0.f;

  auto vload = [&](int nb, int ksn) {
    const int j0n = ksn * 32;
    const int d0 = t;
    gload16(h_oct + ((obase + (j0n >> 3) + (d0 >> 8)) * FD + (d0 & 255)) * 8,
            (char*)(&V_lds[nb][0][0][0]) + d0 * 16);
    const int d1 = t + 512;
    gload16(h_oct + ((obase + (j0n >> 3) + (d1 >> 8)) * FD + (d1 & 255)) * 8,
            (char*)(&V_lds[nb][0][0][0]) + d1 * 16);
  };

  // V[0] issued before anything else (no dependence on s2l)
  vload(0, 0);
  *(float2*)&s2l[t * 2] = *(const float2*)&s2[(size_t)b * NENT + t * 2];
  __syncthreads();                 // s2l visible
  // m_i = leaky(s1_i + max_j s2_j)  (leaky monotone)
  float sm = s2l[lane];
#pragma unroll
  for (int j = 1; j < 16; ++j) sm = fmaxf(sm, s2l[lane + j * 64]);
#pragma unroll
  for (int off = 1; off < 64; off <<= 1) sm = fmaxf(sm, __shfl_xor(sm, off, 64));
  const float q = s1v + sm;
  const float mv = fmaxf(q, ALPHA * q);
  // exp2-domain constants: P = 2^(max(fma(s2j,C1,s1A), fma(s2j,C2,s1B)))
  const float C2v = ALPHA * LOG2E;
  const float mvC = mv * LOG2E;
  const float s1A = s1v * LOG2E - mvC;
  const float s1B = s1v * C2v - mvC;

  auto genp = [&](int nb, int ksn) {
    const int jb = ksn * 32 + gsl * 16;
    float4 qa = *(const float4*)&s2l[jb];
    float4 qb = *(const float4*)&s2l[jb + 4];
    float4 qc = *(const float4*)&s2l[jb + 8];
    float4 qd = *(const float4*)&s2l[jb + 12];
    float zp = 0.f;
    auto pg = [&](float s2j) -> float {
      float vA = fmaf(s2j, LOG2E, s1A);
      float vB = fmaf(s2j, C2v, s1B);
      float r = fexp2(fmaxf(vA, vB));
      zp += r;
      return r;
    };
    bf16x8 pw0, pw1;
    pw0[0] = (__bf16)pg(qa.x); pw0[1] = (__bf16)pg(qa.y);
    pw0[2] = (__bf16)pg(qa.z); pw0[3] = (__bf16)pg(qa.w);
    pw0[4] = (__bf16)pg(qb.x); pw0[5] = (__bf16)pg(qb.y);
    pw0[6] = (__bf16)pg(qb.z); pw0[7] = (__bf16)pg(qb.w);
    pw1[0] = (__bf16)pg(qc.x); pw1[1] = (__bf16)pg(qc.y);
    pw1[2] = (__bf16)pg(qc.z); pw1[3] = (__bf16)pg(qc.w);
    pw1[4] = (__bf16)pg(qd.x); pw1[5] = (__bf16)pg(qd.y);
    pw1[6] = (__bf16)pg(qd.z); pw1[7] = (__bf16)pg(qd.w);
    zsum += zp;
    *(bf16x8*)&P_lds[nb][2 * gsl][irow][0] = pw0;
    *(bf16x8*)&P_lds[nb][2 * gsl + 1][irow][0] = pw1;
  };
  auto mfma_step = [&](int cb) {
    bf16x8 bfv[4];
#pragma unroll
    for (int fj = 0; fj < 4; ++fj)
      bfv[fj] = *(const bf16x8*)&V_lds[cb][g16][wc * 64 + fj * 16 + c15][0];
#pragma unroll
    for (int fi = 0; fi < 8; ++fi) {
      bf16x8 af = *(const bf16x8*)&P_lds[cb][g16][wr * 128 + fi * 16 + c15][0];
#pragma unroll
      for (int fj = 0; fj < 4; ++fj)
        acc[fi][fj] = __builtin_amdgcn_mfma_f32_16x16x32_bf16(
            af, bfv[fj], acc[fi][fj], 0, 0, 0);
    }
  };

  genp(0, 0);
  __syncthreads();                 // P[0] written, V[0] arrived
#pragma unroll 1
  for (int ks2 = 0; ks2 < 16; ++ks2) {
    vload(1, 2 * ks2 + 1);
    genp(1, 2 * ks2 + 1);
    mfma_step(0);
    __syncthreads();
    if (2 * ks2 + 2 < 32) {
      vload(0, 2 * ks2 + 2);
      genp(0, 2 * ks2 + 2);
    }
    mfma_step(1);
    __syncthreads();
  }
  // Z reduction (alias onto P_lds[0]; safe after final barrier)
  float* zred = (float*)&P_lds[0][0][0][0];
  zred[gsl * 256 + irow] = zsum;
  __syncthreads();
  // epilogue: out = acc / Z
#pragma unroll
  for (int fi = 0; fi < 8; ++fi) {
    const int rloc = wr * 128 + fi * 16 + 4 * g16;
    float rz[4];
#pragma unroll
    for (int r = 0; r < 4; ++r)
      rz[r] = __builtin_amdgcn_rcpf(zred[rloc + r] + zred[256 + rloc + r]);
#pragma unroll
    for (int fj = 0; fj < 4; ++fj) {
      const int col = wc * 64 + fj * 16 + c15;
      float* o = out + ((size_t)b * NENT + i0 + rloc) * FD + col;
      o[0 * FD] = acc[fi][fj][0] * rz[0];
      o[1 * FD] = acc[fi][fj][1] * rz[1];
      o[2 * FD] = acc[fi][fj][2] * rz[2];
      o[3 * FD] = acc[fi][fj][3] * rz[3];
    }
  }
}

extern "C" void kernel_launch(void* const* d_in, const int* in_sizes, int n_in,
                              void* d_out, int out_size, void* d_ws, size_t ws_size,
                              hipStream_t stream) {
  const float* x = (const float*)d_in[0];
  const float* W = (const float*)d_in[1];
  const float* a = (const float*)d_in[2];
  float* out = (float*)d_out;

  char* ws = (char*)d_ws;
  u16*   h_oct = (u16*)ws;                       // 32 MB
  float* s1  = (float*)(ws + (size_t)33554432);  // 256 KB
  float* s2  = s1 + NROWS;                       // 256 KB
  float* Wa1 = s2 + NROWS;                       // 1 KB
  float* Wa2 = Wa1 + FD;                         // 1 KB
  u16*   Wt  = (u16*)(Wa2 + FD);                 // 128 KB

  k_wa<<<dim3(256), dim3(256), 0, stream>>>(W, a, Wa1, Wa2);
  k_wt<<<dim3(16), dim3(256), 0, stream>>>(W, Wt);
  k_h<<<dim3(256), dim3(512), 0, stream>>>(x, Wt, Wa1, Wa2, h_oct, s1, s2);
  k_pv<<<dim3(256), dim3(512), 0, stream>>>(h_oct, s1, s2, out);
}